// Round 1
// baseline (61.304 us; speedup 1.0000x reference)
//
#include <hip/hip_runtime.h>
#include <hip/hip_bf16.h>

// Problem constants (fixed by setup_inputs): N=M=8192, D=128, temp scalar, labels[N].
#define N_ROWS 8192
#define M_COLS 8192
#define D_DIM  128
#define BM 64          // rows per block (4 waves x 16)
#define BN 64          // cols per LDS tile
#define MSPLIT 8       // column-split for parallelism (partial LSE sums merge since max is fixed at 0)
#define MCHUNK (M_COLS / MSPLIT)   // 1024 cols per block

typedef __attribute__((ext_vector_type(8))) short short8;   // 8 x bf16 (4 VGPRs) MFMA A/B frag
typedef __attribute__((ext_vector_type(4))) float f32x4;    // MFMA C/D frag

// ---------------- prep: fp32 -> bf16 copies + row squared norms ----------------
// grid = 16384 blocks of 64 (one wave per row; blocks >= 8192 handle feat2)
__global__ void prep_kernel(const float* __restrict__ feat, const float* __restrict__ feat2,
                            ushort* __restrict__ fb, ushort* __restrict__ f2b,
                            float* __restrict__ xsq, float* __restrict__ ysq) {
    int row   = blockIdx.x & (N_ROWS - 1);
    bool two  = blockIdx.x >= N_ROWS;
    const float* src = two ? feat2 : feat;
    ushort* dst      = two ? f2b  : fb;
    float* sq        = two ? ysq  : xsq;
    int l = threadIdx.x;                       // 0..63
    float2 v = reinterpret_cast<const float2*>(src + row * D_DIM)[l];
    __hip_bfloat16 b0 = __float2bfloat16(v.x);
    __hip_bfloat16 b1 = __float2bfloat16(v.y);
    ushort2 b;
    b.x = *reinterpret_cast<ushort*>(&b0);
    b.y = *reinterpret_cast<ushort*>(&b1);
    reinterpret_cast<ushort2*>(dst + row * D_DIM)[l] = b;
    float p = v.x * v.x + v.y * v.y;
    #pragma unroll
    for (int off = 1; off < 64; off <<= 1) p += __shfl_xor(p, off);
    if (l == 0) sq[row] = p;
}

// ---------------- picked-label distances, exact fp32 ----------------
// grid = 8192 blocks of 64; pick[i] = temp * ||feat_i - feat2_{label_i}||
__global__ void pick_kernel(const float* __restrict__ feat, const float* __restrict__ feat2,
                            const int* __restrict__ labels, const float* __restrict__ temp_p,
                            float* __restrict__ pick) {
    int row = blockIdx.x;
    int l = threadIdx.x;
    int lab = labels[row];
    float2 x = reinterpret_cast<const float2*>(feat + row * D_DIM)[l];
    float2 y = reinterpret_cast<const float2*>(feat2 + lab * D_DIM)[l];
    float dx = x.x - y.x, dy = x.y - y.y;
    float p = dx * dx + dy * dy;
    #pragma unroll
    for (int off = 1; off < 64; off <<= 1) p += __shfl_xor(p, off);
    if (l == 0) pick[row] = (*temp_p) * __builtin_amdgcn_sqrtf(p);
}

// ---------------- fused GEMM + dist + exp2 accumulation ----------------
// grid = (N/BM) * MSPLIT = 1024 blocks of 256 (4 waves).
// Block (rowTile, ms): rows rowTile*64..+63, cols ms*1024..+1023.
// Each wave owns 16 rows: A-fragments live in registers across the whole M loop.
// B tile (64 cols x 128 k, bf16) staged in LDS with XOR swizzle (G4 fix for the
// 256B-row 32-way bank conflict): byte_in_row ^= (row&7)<<4  -> 2-way (free).
// Per-lane running s[4] = sum over its columns of exp2(log2e * (-temp*dist));
// max fixed at 0 since logits <= 0. Merged across the 16 column-lanes at the end.
__global__ __launch_bounds__(256) void
main_kernel(const ushort* __restrict__ fb, const ushort* __restrict__ f2b,
            const float* __restrict__ xsq, const float* __restrict__ ysq,
            const float* __restrict__ temp_p, float* __restrict__ spart) {
    __shared__ ushort lds[BN * D_DIM];   // 16 KiB

    int bid = blockIdx.x;
    int rowTile = bid / MSPLIT;
    int ms = bid % MSPLIT;
    int tid = threadIdx.x;
    int wave = tid >> 6, lane = tid & 63;
    int lrow = lane & 15, lgrp = lane >> 4;

    int rowBase = rowTile * BM + wave * 16;

    // A fragments: lane holds A row (lrow), k = 32*ks + 8*lgrp .. +7  (16B contiguous)
    short8 a[4];
    const ushort* arow = fb + (rowBase + lrow) * D_DIM;
    #pragma unroll
    for (int ks = 0; ks < 4; ++ks)
        a[ks] = *reinterpret_cast<const short8*>(arow + ks * 32 + lgrp * 8);

    // per-lane row squared norms: C rows are lgrp*4 + r
    float xs[4];
    #pragma unroll
    for (int r = 0; r < 4; ++r) xs[r] = xsq[rowBase + lgrp * 4 + r];

    float temp = *temp_p;
    float cl2 = -temp * 1.4426950408889634f;   // -temp * log2(e)

    float s[4] = {0.f, 0.f, 0.f, 0.f};

    for (int mt = 0; mt < MCHUNK / BN; ++mt) {    // 16 tiles
        int mBase = ms * MCHUNK + mt * BN;
        __syncthreads();   // protect LDS from previous tile's readers
        // stage 64x128 bf16 tile: 1024 chunks of 16B, 256 threads x 4 passes
        #pragma unroll
        for (int p = 0; p < 4; ++p) {
            int idx = p * 256 + tid;
            int n  = idx >> 4;              // row (output col) 0..63
            int cb = (idx & 15) << 4;       // byte in row, 16B aligned
            int sb = cb ^ ((n & 7) << 4);   // swizzle
            short8 v = *reinterpret_cast<const short8*>(
                reinterpret_cast<const short*>(f2b) + (mBase + n) * D_DIM + (cb >> 1));
            *reinterpret_cast<short8*>(reinterpret_cast<char*>(lds) + n * 256 + sb) = v;
        }
        __syncthreads();

        #pragma unroll
        for (int f = 0; f < 4; ++f) {
            f32x4 acc = {0.f, 0.f, 0.f, 0.f};
            #pragma unroll
            for (int ks = 0; ks < 4; ++ks) {
                int n  = f * 16 + lrow;                 // B col
                int cb = ks * 64 + lgrp * 16;           // byte: k = 32*ks + 8*lgrp
                int sb = cb ^ ((n & 7) << 4);
                short8 b = *reinterpret_cast<const short8*>(
                    reinterpret_cast<const char*>(lds) + n * 256 + sb);
                acc = __builtin_amdgcn_mfma_f32_16x16x32_bf16(a[ks], b, acc, 0, 0, 0);
            }
            float ys = ysq[mBase + f * 16 + lrow];
            #pragma unroll
            for (int r = 0; r < 4; ++r) {
                float sq = xs[r] + ys - 2.0f * acc[r];
                float d  = __builtin_amdgcn_sqrtf(fmaxf(sq, 0.0f));
                s[r] += __builtin_amdgcn_exp2f(cl2 * d);
            }
        }
    }

    // merge the 16 column-lanes (same lgrp share the same 4 rows)
    #pragma unroll
    for (int off = 1; off < 16; off <<= 1)
        #pragma unroll
        for (int r = 0; r < 4; ++r) s[r] += __shfl_xor(s[r], off);

    if (lrow == 0) {
        #pragma unroll
        for (int r = 0; r < 4; ++r)
            spart[ms * N_ROWS + rowBase + lgrp * 4 + r] = s[r];
    }
}

// ---------------- finish: per-row LSE + picked, deterministic tree reduce ----------------
__global__ void finish_kernel(const float* __restrict__ spart, const float* __restrict__ pick,
                              float* __restrict__ out) {
    __shared__ float red[16];
    int tid = threadIdx.x;   // 1024
    float local = 0.f;
    for (int i = tid; i < N_ROWS; i += 1024) {
        float s = 0.f;
        #pragma unroll
        for (int m = 0; m < MSPLIT; ++m) s += spart[m * N_ROWS + i];
        // s = sum exp(logit); lse = ln(s); loss_i = lse + temp*dist_label
        local += __builtin_amdgcn_logf(s) * 0.6931471805599453f + pick[i];
    }
    #pragma unroll
    for (int off = 1; off < 64; off <<= 1) local += __shfl_xor(local, off);
    if ((tid & 63) == 0) red[tid >> 6] = local;
    __syncthreads();
    if (tid < 16) {
        float v = red[tid];
        #pragma unroll
        for (int off = 1; off < 16; off <<= 1) v += __shfl_xor(v, off);
        if (tid == 0) out[0] = v / (float)N_ROWS;
    }
}

extern "C" void kernel_launch(void* const* d_in, const int* in_sizes, int n_in,
                              void* d_out, int out_size, void* d_ws, size_t ws_size,
                              hipStream_t stream) {
    const float* feat   = (const float*)d_in[0];
    const float* feat2  = (const float*)d_in[1];
    const float* temp   = (const float*)d_in[2];
    const int*   labels = (const int*)d_in[3];
    float* out = (float*)d_out;

    char* ws = (char*)d_ws;
    ushort* fb  = (ushort*)ws;                          // 2 MiB
    ushort* f2b = fb + (size_t)N_ROWS * D_DIM;          // 2 MiB
    float* xsq   = (float*)(ws + 4u * 1024 * 1024);     // 32 KiB
    float* ysq   = xsq + N_ROWS;                        // 32 KiB
    float* spart = ysq + M_COLS;                        // MSPLIT*N 32-bit = 256 KiB
    float* pick  = spart + (size_t)MSPLIT * N_ROWS;     // 32 KiB

    prep_kernel<<<2 * N_ROWS, 64, 0, stream>>>(feat, feat2, fb, f2b, xsq, ysq);
    pick_kernel<<<N_ROWS, 64, 0, stream>>>(feat, feat2, labels, temp, pick);
    main_kernel<<<(N_ROWS / BM) * MSPLIT, 256, 0, stream>>>(fb, f2b, xsq, ysq, temp, spart);
    finish_kernel<<<1, 1024, 0, stream>>>(spart, pick, out);
}

// Round 2
// 58.768 us; speedup vs baseline: 1.0431x; 1.0431x over previous
//
#include <hip/hip_runtime.h>
#include <hip/hip_bf16.h>

// N=M=8192, D=128. Loss = mean_i [ ln(sum_j exp(-temp*dist_ij)) + temp*dist_i,lab_i ]
#define NR 8192
#define MC 8192
#define DD 128
#define MSPLIT 32                 // column split; grid = 32 rowblocks x 32
#define CPB (MC / MSPLIT)         // 256 cols per block
#define TILES (CPB / 32)          // 8 col-tiles of 32

typedef __attribute__((ext_vector_type(8))) short short8;    // 8 bf16 = 4 VGPRs (MFMA A/B frag)
typedef __attribute__((ext_vector_type(16))) float f32x16;   // 32x32 MFMA C/D frag

// ---------------- prep: bf16 casts, pre-scaled norms, picked-label dist ----------------
// wave per row; 4 waves/block; grid 2048.
// xsq2 = c^2*||x||^2, ysq2 = c^2*||y||^2 with c = temp*log2(e); consts[0] = -2c^2.
__global__ __launch_bounds__(256) void prep_kernel(
    const float* __restrict__ feat, const float* __restrict__ feat2,
    const float* __restrict__ temp_p, const int* __restrict__ labels,
    ushort* __restrict__ fb, ushort* __restrict__ f2b,
    float* __restrict__ xsq2, float* __restrict__ ysq2,
    float* __restrict__ pick, float* __restrict__ consts) {
    int row = blockIdx.x * 4 + (threadIdx.x >> 6);
    int l = threadIdx.x & 63;
    float temp = *temp_p;
    float c = temp * 1.4426950408889634f;   // temp * log2(e)
    float c2 = c * c;
    int lab = labels[row];
    float2 x = ((const float2*)(feat  + (size_t)row * DD))[l];
    float2 y = ((const float2*)(feat2 + (size_t)row * DD))[l];
    float2 z = ((const float2*)(feat2 + (size_t)lab * DD))[l];
    __hip_bfloat16 bx0 = __float2bfloat16(x.x), bx1 = __float2bfloat16(x.y);
    __hip_bfloat16 by0 = __float2bfloat16(y.x), by1 = __float2bfloat16(y.y);
    ushort2 ux, uy;
    ux.x = *(ushort*)&bx0; ux.y = *(ushort*)&bx1;
    uy.x = *(ushort*)&by0; uy.y = *(ushort*)&by1;
    ((ushort2*)(fb  + (size_t)row * DD))[l] = ux;
    ((ushort2*)(f2b + (size_t)row * DD))[l] = uy;
    float sx = x.x * x.x + x.y * x.y;
    float sy = y.x * y.x + y.y * y.y;
    float d0 = x.x - z.x, d1 = x.y - z.y;
    float sd = d0 * d0 + d1 * d1;
    #pragma unroll
    for (int off = 1; off < 64; off <<= 1) {
        sx += __shfl_xor(sx, off);
        sy += __shfl_xor(sy, off);
        sd += __shfl_xor(sd, off);
    }
    if (l == 0) {
        xsq2[row] = c2 * sx;
        ysq2[row] = c2 * sy;
        pick[row] = temp * __builtin_amdgcn_sqrtf(sd);   // exact fp32 picked distance
        if (row == 0) consts[0] = -2.0f * c2;
    }
}

// ---------------- main: register-resident A, global-direct B, fused epilogue ----------------
// Wave: 64 rows (2 MFMA row-tiles) x 256 cols (8 col-tiles of 32), 32x32x16 bf16 MFMA.
// No LDS, no barriers. A frags (64 VGPRs) + pre-scaled row norms held for whole kernel.
// Per element epilogue: fma, fmax, v_sqrt, v_exp(-) , add  (3-4 VALU + 2 trans).
// A-frag layout (32x32x16): row = lane&31, k = (lane>>5)*8 + j. B symmetric (col = lane&31).
// C/D: col = lane&31, row = (r&3) + 8*(r>>2) + 4*(lane>>5)   [m74/m101 verified]
__global__ __launch_bounds__(256, 2) void main_kernel(
    const ushort* __restrict__ fb, const ushort* __restrict__ f2b,
    const float* __restrict__ xsq2, const float* __restrict__ ysq2,
    const float* __restrict__ consts, float* __restrict__ spart) {
    int bid = blockIdx.x;
    int cs = bid & (MSPLIT - 1);
    int rowblock = bid >> 5;
    int tid = threadIdx.x;
    int wave = tid >> 6, lane = tid & 63;
    int lrow = lane & 31, lhalf = lane >> 5;
    int rowbase = rowblock * 256 + wave * 64;
    int colbase0 = cs * CPB;
    float m2c = consts[0];

    // A fragments, whole K, 2 row-tiles: 64 VGPRs, loaded once
    short8 a[2][8];
    const ushort* ap = fb + (size_t)(rowbase + lrow) * DD + lhalf * 8;
    #pragma unroll
    for (int rt = 0; rt < 2; ++rt)
        #pragma unroll
        for (int ks = 0; ks < 8; ++ks)
            a[rt][ks] = *(const short8*)(ap + rt * 32 * DD + ks * 16);

    // pre-scaled row norms for this lane's C rows
    float xs2[2][16];
    #pragma unroll
    for (int rt = 0; rt < 2; ++rt)
        #pragma unroll
        for (int r = 0; r < 16; ++r)
            xs2[rt][r] = xsq2[rowbase + rt * 32 + (r & 3) + 8 * (r >> 2) + 4 * lhalf];

    float s[2][16];
    #pragma unroll
    for (int rt = 0; rt < 2; ++rt)
        #pragma unroll
        for (int r = 0; r < 16; ++r) s[rt][r] = 0.f;

    for (int t = 0; t < TILES; ++t) {
        int colbase = colbase0 + t * 32;
        float ys2 = ysq2[colbase + lrow];
        const ushort* bp = f2b + (size_t)(colbase + lrow) * DD + lhalf * 8;
        short8 b[8];
        #pragma unroll
        for (int ks = 0; ks < 8; ++ks)
            b[ks] = *(const short8*)(bp + ks * 16);

        f32x16 acc0, acc1;
        #pragma unroll
        for (int r = 0; r < 16; ++r) { acc0[r] = 0.f; acc1[r] = 0.f; }
        #pragma unroll
        for (int ks = 0; ks < 8; ++ks) {
            acc0 = __builtin_amdgcn_mfma_f32_32x32x16_bf16(a[0][ks], b[ks], acc0, 0, 0, 0);
            acc1 = __builtin_amdgcn_mfma_f32_32x32x16_bf16(a[1][ks], b[ks], acc1, 0, 0, 0);
        }
        #pragma unroll
        for (int r = 0; r < 16; ++r) {
            float sq0 = fmaxf(fmaf(m2c, acc0[r], xs2[0][r] + ys2), 0.f);
            float sq1 = fmaxf(fmaf(m2c, acc1[r], xs2[1][r] + ys2), 0.f);
            s[0][r] += __builtin_amdgcn_exp2f(-__builtin_amdgcn_sqrtf(sq0));
            s[1][r] += __builtin_amdgcn_exp2f(-__builtin_amdgcn_sqrtf(sq1));
        }
    }

    // reduce exp-sums across the 32 column-lanes of each half-wave
    #pragma unroll
    for (int off = 1; off <= 16; off <<= 1)
        #pragma unroll
        for (int rt = 0; rt < 2; ++rt)
            #pragma unroll
            for (int r = 0; r < 16; ++r)
                s[rt][r] += __shfl_xor(s[rt][r], off);

    if (lrow == 0) {
        float* sp = spart + (size_t)cs * NR + rowbase;
        #pragma unroll
        for (int rt = 0; rt < 2; ++rt)
            #pragma unroll
            for (int r = 0; r < 16; ++r)
                sp[rt * 32 + (r & 3) + 8 * (r >> 2) + 4 * lhalf] = s[rt][r];
    }
}

// ---------------- finish: per-row LSE + picked, two-stage deterministic reduce ----------------
__global__ void finish1_kernel(const float* __restrict__ spart,
                               const float* __restrict__ pick,
                               float* __restrict__ partial) {
    __shared__ float red[2];
    int row = blockIdx.x * 128 + threadIdx.x;
    float ssum = 0.f;
    #pragma unroll
    for (int ms = 0; ms < MSPLIT; ++ms)
        ssum += spart[(size_t)ms * NR + row];
    float v = __builtin_amdgcn_logf(ssum) * 0.6931471805599453f + pick[row];
    #pragma unroll
    for (int off = 1; off < 64; off <<= 1) v += __shfl_xor(v, off);
    if ((threadIdx.x & 63) == 0) red[threadIdx.x >> 6] = v;
    __syncthreads();
    if (threadIdx.x == 0) partial[blockIdx.x] = red[0] + red[1];
}

__global__ void finish2_kernel(const float* __restrict__ partial, float* __restrict__ out) {
    float v = partial[threadIdx.x];   // 64 entries
    #pragma unroll
    for (int off = 1; off < 64; off <<= 1) v += __shfl_xor(v, off);
    if (threadIdx.x == 0) out[0] = v * (1.0f / NR);
}

extern "C" void kernel_launch(void* const* d_in, const int* in_sizes, int n_in,
                              void* d_out, int out_size, void* d_ws, size_t ws_size,
                              hipStream_t stream) {
    const float* feat   = (const float*)d_in[0];
    const float* feat2  = (const float*)d_in[1];
    const float* temp   = (const float*)d_in[2];
    const int*   labels = (const int*)d_in[3];
    float* out = (float*)d_out;

    char* ws = (char*)d_ws;
    ushort* fb   = (ushort*)ws;                              // 2 MiB
    ushort* f2b  = (ushort*)(ws + (1u << 21));               // 2 MiB
    float*  xsq2 = (float*)(ws + (1u << 22));                // 32 KiB
    float*  ysq2 = xsq2 + NR;                                // 32 KiB
    float*  pick = ysq2 + MC;                                // 32 KiB
    float*  partial = pick + NR;                             // 64 floats
    float*  consts  = partial + 64;                          // 1 float
    float*  spart = (float*)(ws + (9u << 19));               // @4.5MiB, 1 MiB

    prep_kernel<<<NR / 4, 256, 0, stream>>>(feat, feat2, temp, labels,
                                            fb, f2b, xsq2, ysq2, pick, consts);
    main_kernel<<<(NR / 256) * MSPLIT, 256, 0, stream>>>(fb, f2b, xsq2, ysq2, consts, spart);
    finish1_kernel<<<NR / 128, 128, 0, stream>>>(spart, pick, partial);
    finish2_kernel<<<1, 64, 0, stream>>>(partial, out);
}